// Round 2
// baseline (931.883 us; speedup 1.0000x reference)
//
#include <hip/hip_runtime.h>
#include <hip/hip_bf16.h>

typedef __hip_bfloat16 bf16;

#define NB 8
#define NC 256
#define ND 32
#define NH 8
#define NN 16384

__device__ __forceinline__ float u2f(unsigned short u) {
  union { unsigned int i; float f; } v; v.i = ((unsigned int)u) << 16; return v.f;
}
__device__ __forceinline__ unsigned short f2u(float f) {
  union { float f; unsigned int i; } v; v.f = f;
  unsigned int x = v.i;
  return (unsigned short)((x + 0x7fffu + ((x >> 16) & 1u)) >> 16);  // RNE
}
// generic scalar load: isbf ? bf16[i] : float[i]
__device__ __forceinline__ float ldg(const void* p, size_t i, int isbf) {
  return isbf ? u2f(((const unsigned short*)p)[i]) : ((const float*)p)[i];
}

// ---------------- dtype detect: low-16 exponent-field statistics ----------------
__global__ __launch_bounds__(256) void detect_kernel(const void* __restrict__ x,
                                                     int* __restrict__ flag) {
  __shared__ int red[4];
  const unsigned int* w = (const unsigned int*)x;
  int cnt = 0;
  for (int i = threadIdx.x; i < 4096; i += 256) {
    unsigned int e = (w[i] >> 7) & 0xFFu;  // exp field of LOW bf16 half
    cnt += (e >= 100u && e <= 135u) ? 1 : 0;
  }
  for (int off = 32; off; off >>= 1) cnt += __shfl_xor(cnt, off, 64);
  if ((threadIdx.x & 63) == 0) red[threadIdx.x >> 6] = cnt;
  __syncthreads();
  if (threadIdx.x == 0)
    flag[0] = (red[0] + red[1] + red[2] + red[3] > 2048) ? 1 : 0;
}

// ---------------- prep: WT[c][o] = w[o][c] * scale[o], fp32 ----------------
__global__ __launch_bounds__(256) void prep_weights(
    const void* __restrict__ wq, const void* __restrict__ q_scale,
    const void* __restrict__ wp, const void* __restrict__ p_scale,
    const int* __restrict__ flag, float* __restrict__ WqT, float* __restrict__ WpT) {
  int isbf = flag[0];
  int idx = blockIdx.x * 256 + threadIdx.x;  // 512 blocks -> 131072
  int mat = idx >> 16;
  int r = idx & 65535;
  int c = r >> 8, o = r & 255;
  const void* w = mat ? wp : wq;
  const void* sc = mat ? p_scale : q_scale;
  float* WT = mat ? WpT : WqT;
  WT[c * NC + o] = ldg(w, o * NC + c, isbf) * ldg(sc, o, isbf);
}

// ---------------- kv = affine(Wkv @ X) : [B][32][N] fp32 ----------------
#define KV_ACC(X0, X1)                                                  \
  do {                                                                  \
    const float4* wr = (const float4*)&wl[c][0];                        \
    _Pragma("unroll") for (int k = 0; k < 8; k++) {                     \
      float4 w4 = wr[k];                                                \
      acc0[4 * k + 0] += w4.x * (X0); acc1[4 * k + 0] += w4.x * (X1);   \
      acc0[4 * k + 1] += w4.y * (X0); acc1[4 * k + 1] += w4.y * (X1);   \
      acc0[4 * k + 2] += w4.z * (X0); acc1[4 * k + 2] += w4.z * (X1);   \
      acc0[4 * k + 3] += w4.w * (X0); acc1[4 * k + 3] += w4.w * (X1);   \
    }                                                                   \
  } while (0)

__global__ __launch_bounds__(256, 2) void kv_kernel(
    const void* __restrict__ x, const void* __restrict__ wkv,
    const void* __restrict__ kv_scale, const void* __restrict__ kv_bias,
    const int* __restrict__ flag, float* __restrict__ kv_out) {
  __shared__ float wl[NC][ND];  // [c][d], scale folded
  int isbf = flag[0];
  int tid = threadIdx.x;
  int b = blockIdx.x >> 5;
  int n0 = (blockIdx.x & 31) * 512;
  {
    int d = tid >> 3, cb = (tid & 7) * 32;
    float s = ldg(kv_scale, d, isbf);
    for (int i = 0; i < 32; i++)
      wl[cb + i][d] = ldg(wkv, d * NC + cb + i, isbf) * s;
  }
  __syncthreads();
  float acc0[ND], acc1[ND];
#pragma unroll
  for (int d = 0; d < ND; d++) { acc0[d] = 0.f; acc1[d] = 0.f; }
  size_t base = (size_t)b * NC * NN + n0 + tid * 2;
  if (isbf) {
    const unsigned short* xp = (const unsigned short*)x + base;
    for (int c = 0; c < NC; c++) {
      unsigned int u = *(const unsigned int*)(xp + (size_t)c * NN);
      float x0 = u2f((unsigned short)(u & 0xffffu));
      float x1 = u2f((unsigned short)(u >> 16));
      KV_ACC(x0, x1);
    }
  } else {
    const float* xp = (const float*)x + base;
    for (int c = 0; c < NC; c++) {
      float2 v = *(const float2*)(xp + (size_t)c * NN);
      KV_ACC(v.x, v.y);
    }
  }
  int n = n0 + tid * 2;
#pragma unroll
  for (int d = 0; d < ND; d++) {
    float bias = ldg(kv_bias, d, isbf);
    float2 v = make_float2(acc0[d] + bias, acc1[d] + bias);
    *(float2*)(kv_out + ((size_t)(b * ND + d)) * NN + n) = v;
  }
}

// ---------------- rowmax over N per (b,d) ----------------
__global__ __launch_bounds__(256) void rowmax_kernel(const float* __restrict__ kv,
                                                     float* __restrict__ m) {
  __shared__ float red[4];
  int row = blockIdx.x;  // b*32+d
  const float* p = kv + (size_t)row * NN;
  float mx = -3.0e38f;
  for (int i = threadIdx.x; i < NN; i += 256) mx = fmaxf(mx, p[i]);
  for (int off = 32; off; off >>= 1) mx = fmaxf(mx, __shfl_xor(mx, off, 64));
  if ((threadIdx.x & 63) == 0) red[threadIdx.x >> 6] = mx;
  __syncthreads();
  if (threadIdx.x == 0)
    m[row] = fmaxf(fmaxf(red[0], red[1]), fmaxf(red[2], red[3]));
}

// ---------------- partial S[d][e] = sum exp(kv_d - m_d) * kv_e ; Z[d] ----------------
__global__ __launch_bounds__(256) void ctx_partial(const float* __restrict__ kv,
                                                   const float* __restrict__ m,
                                                   float* __restrict__ S,
                                                   float* __restrict__ Z) {
  __shared__ float kvt[ND][257];
  __shared__ float et[ND][257];
  int b = blockIdx.x >> 6;
  int n0 = (blockIdx.x & 63) * 256;
  int tid = threadIdx.x;
  for (int r = 0; r < ND; r++) {
    float v = kv[((size_t)(b * ND + r)) * NN + n0 + tid];
    kvt[r][tid] = v;
    et[r][tid] = __expf(v - m[b * ND + r]);
  }
  __syncthreads();
  int e = tid & 31, dq = tid >> 5;  // d in [4*dq, 4*dq+4)
  float acc[4] = {0.f, 0.f, 0.f, 0.f};
  for (int n = 0; n < 256; n++) {
    float kve = kvt[e][n];
#pragma unroll
    for (int k = 0; k < 4; k++) acc[k] += et[4 * dq + k][n] * kve;
  }
#pragma unroll
  for (int k = 0; k < 4; k++)
    atomicAdd(&S[((size_t)b * ND + 4 * dq + k) * ND + e], acc[k]);
  if (tid < ND) {
    float z = 0.f;
    for (int n = 0; n < 256; n++) z += et[tid][n];
    atomicAdd(&Z[b * ND + tid], z);
  }
}

__global__ __launch_bounds__(256) void ctx_finalize(const float* __restrict__ S,
                                                    const float* __restrict__ Z,
                                                    float* __restrict__ ctx) {
  int i = blockIdx.x * 256 + threadIdx.x;  // 8192 total
  ctx[i] = S[i] / Z[i >> 5];
}

// ---------------- fused: q GEMM -> softmax(D) -> ctx matvec -> relu -> out GEMM ----------------
__global__ __launch_bounds__(256, 2) void fused_main(
    const void* __restrict__ x, const float* __restrict__ WqT,
    const void* __restrict__ q_bias, const float* __restrict__ ctx,
    const float* __restrict__ WpT, const void* __restrict__ p_bias,
    const int* __restrict__ flag, void* __restrict__ out) {
  __shared__ float tile[NC][68];     // x, then q, then relu(att); [channel][pixel]
  __shared__ float ctx_l[ND][ND];    // ctx[d][e]
  __shared__ float qb_l[NC];
  int isbf = flag[0];
  int tid = threadIdx.x;
  int b = blockIdx.x >> 8;
  int n0 = (blockIdx.x & 255) * 64;

  ((float4*)ctx_l)[tid] = ((const float4*)(ctx + (size_t)b * ND * ND))[tid];
  qb_l[tid] = ldg(q_bias, tid, isbf);

  {
    int p4 = (tid & 15) * 4;
    int cb = tid >> 4;
    if (isbf) {
#pragma unroll
      for (int k = 0; k < 16; k++) {
        int c = k * 16 + cb;
        const unsigned short* src =
            (const unsigned short*)x + ((size_t)b * NC + c) * NN + n0 + p4;
        ushort4 u = *(const ushort4*)src;
        tile[c][p4 + 0] = u2f(u.x);
        tile[c][p4 + 1] = u2f(u.y);
        tile[c][p4 + 2] = u2f(u.z);
        tile[c][p4 + 3] = u2f(u.w);
      }
    } else {
#pragma unroll
      for (int k = 0; k < 16; k++) {
        int c = k * 16 + cb;
        const float* src = (const float*)x + ((size_t)b * NC + c) * NN + n0 + p4;
        float4 v = *(const float4*)src;
        tile[c][p4 + 0] = v.x;
        tile[c][p4 + 1] = v.y;
        tile[c][p4 + 2] = v.z;
        tile[c][p4 + 3] = v.w;
      }
    }
  }
  __syncthreads();

  int i = tid >> 3, j = tid & 7;
  int o0 = i * 8, p0 = j * 8;
  float acc[8][8];
#pragma unroll
  for (int a = 0; a < 8; a++)
#pragma unroll
    for (int bb = 0; bb < 8; bb++) acc[a][bb] = 0.f;

  // GEMM1: q = WqT^T @ x_tile
  for (int c = 0; c < NC; c++) {
    float4 w0 = *(const float4*)(WqT + c * NC + o0);
    float4 w1 = *(const float4*)(WqT + c * NC + o0 + 4);
    float4 x0 = *(const float4*)&tile[c][p0];
    float4 x1 = *(const float4*)&tile[c][p0 + 4];
    float wv[8] = {w0.x, w0.y, w0.z, w0.w, w1.x, w1.y, w1.z, w1.w};
    float xv[8] = {x0.x, x0.y, x0.z, x0.w, x1.x, x1.y, x1.z, x1.w};
#pragma unroll
    for (int a = 0; a < 8; a++)
#pragma unroll
      for (int bb = 0; bb < 8; bb++) acc[a][bb] += wv[a] * xv[bb];
  }
  __syncthreads();  // all reads of x done
#pragma unroll
  for (int a = 0; a < 8; a++) {
    *(float4*)&tile[o0 + a][p0] = make_float4(acc[a][0], acc[a][1], acc[a][2], acc[a][3]);
    *(float4*)&tile[o0 + a][p0 + 4] = make_float4(acc[a][4], acc[a][5], acc[a][6], acc[a][7]);
  }
  __syncthreads();

  // softmax over D per (head,pixel) + ctx matvec + relu, in place
  for (int pair = 0; pair < 2; pair++) {
    int pid = tid + pair * 256;
    int h = pid >> 6, p = pid & 63;
    float qv[ND];
#pragma unroll
    for (int d = 0; d < ND; d++) qv[d] = tile[h * ND + d][p] + qb_l[h * ND + d];
    float mx = qv[0];
#pragma unroll
    for (int d = 1; d < ND; d++) mx = fmaxf(mx, qv[d]);
    float s = 0.f;
#pragma unroll
    for (int d = 0; d < ND; d++) { qv[d] = __expf(qv[d] - mx); s += qv[d]; }
    float inv = 1.f / s;
    float4 a4[8];
#pragma unroll
    for (int k = 0; k < 8; k++) a4[k] = make_float4(0.f, 0.f, 0.f, 0.f);
#pragma unroll
    for (int d = 0; d < ND; d++) {
      float ev = qv[d];
      const float4* cr = (const float4*)&ctx_l[d][0];
#pragma unroll
      for (int k = 0; k < 8; k++) {
        float4 cv = cr[k];
        a4[k].x += cv.x * ev; a4[k].y += cv.y * ev;
        a4[k].z += cv.z * ev; a4[k].w += cv.w * ev;
      }
    }
#pragma unroll
    for (int k = 0; k < 8; k++) {
      tile[h * ND + 4 * k + 0][p] = fmaxf(a4[k].x * inv, 0.f);
      tile[h * ND + 4 * k + 1][p] = fmaxf(a4[k].y * inv, 0.f);
      tile[h * ND + 4 * k + 2][p] = fmaxf(a4[k].z * inv, 0.f);
      tile[h * ND + 4 * k + 3][p] = fmaxf(a4[k].w * inv, 0.f);
    }
  }
  __syncthreads();

  // GEMM2: out = WpT^T @ y_tile + p_bias
#pragma unroll
  for (int a = 0; a < 8; a++)
#pragma unroll
    for (int bb = 0; bb < 8; bb++) acc[a][bb] = 0.f;
  for (int c = 0; c < NC; c++) {
    float4 w0 = *(const float4*)(WpT + c * NC + o0);
    float4 w1 = *(const float4*)(WpT + c * NC + o0 + 4);
    float4 x0 = *(const float4*)&tile[c][p0];
    float4 x1 = *(const float4*)&tile[c][p0 + 4];
    float wv[8] = {w0.x, w0.y, w0.z, w0.w, w1.x, w1.y, w1.z, w1.w};
    float xv[8] = {x0.x, x0.y, x0.z, x0.w, x1.x, x1.y, x1.z, x1.w};
#pragma unroll
    for (int a = 0; a < 8; a++)
#pragma unroll
      for (int bb = 0; bb < 8; bb++) acc[a][bb] += wv[a] * xv[bb];
  }
#pragma unroll
  for (int a = 0; a < 8; a++) {
    int o = o0 + a;
    float pb = ldg(p_bias, o, isbf);
    size_t off = ((size_t)b * NC + o) * NN + n0 + p0;
    if (isbf) {
      unsigned short o8[8];
#pragma unroll
      for (int k = 0; k < 8; k++) o8[k] = f2u(acc[a][k] + pb);
      uint4 pack;
      pack.x = (unsigned)o8[0] | ((unsigned)o8[1] << 16);
      pack.y = (unsigned)o8[2] | ((unsigned)o8[3] << 16);
      pack.z = (unsigned)o8[4] | ((unsigned)o8[5] << 16);
      pack.w = (unsigned)o8[6] | ((unsigned)o8[7] << 16);
      *(uint4*)((unsigned short*)out + off) = pack;
    } else {
      float* po = (float*)out + off;
      *(float4*)po = make_float4(acc[a][0] + pb, acc[a][1] + pb,
                                 acc[a][2] + pb, acc[a][3] + pb);
      *(float4*)(po + 4) = make_float4(acc[a][4] + pb, acc[a][5] + pb,
                                       acc[a][6] + pb, acc[a][7] + pb);
    }
  }
}

extern "C" void kernel_launch(void* const* d_in, const int* in_sizes, int n_in,
                              void* d_out, int out_size, void* d_ws, size_t ws_size,
                              hipStream_t stream) {
  const void* input   = d_in[0];
  const void* wq      = d_in[1];
  const void* q_scale = d_in[2];
  const void* q_bias  = d_in[3];
  const void* wkv     = d_in[4];
  const void* kv_scale= d_in[5];
  const void* kv_bias = d_in[6];
  const void* wp      = d_in[7];
  const void* p_scale = d_in[8];
  const void* p_bias  = d_in[9];

  char* w = (char*)d_ws;
  int*  flag = (int*)w;     w += 256;
  float* kv   = (float*)w;  w += (size_t)NB * ND * NN * 4;   // 16 MiB
  float* mrow = (float*)w;  w += 256 * 4;
  float* S    = (float*)w;  // S then Z contiguous for one memset
  float* Z    = (float*)(w + (size_t)NB * ND * ND * 4);
  w += (size_t)NB * ND * ND * 4 + NB * ND * 4;
  float* ctx  = (float*)w;  w += (size_t)NB * ND * ND * 4;
  float* WqT  = (float*)w;  w += (size_t)NC * NC * 4;
  float* WpT  = (float*)w;  w += (size_t)NC * NC * 4;

  hipMemsetAsync(S, 0, (size_t)NB * ND * ND * 4 + NB * ND * 4, stream);
  detect_kernel<<<1, 256, 0, stream>>>(input, flag);
  prep_weights<<<512, 256, 0, stream>>>(wq, q_scale, wp, p_scale, flag, WqT, WpT);
  kv_kernel<<<256, 256, 0, stream>>>(input, wkv, kv_scale, kv_bias, flag, kv);
  rowmax_kernel<<<256, 256, 0, stream>>>(kv, mrow);
  ctx_partial<<<512, 256, 0, stream>>>(kv, mrow, S, Z);
  ctx_finalize<<<32, 256, 0, stream>>>(S, Z, ctx);
  fused_main<<<2048, 256, 0, stream>>>(input, WqT, q_bias, ctx, WpT, p_bias, flag, (void*)d_out);
}